// Round 3
// baseline (373.488 us; speedup 1.0000x reference)
//
#include <hip/hip_runtime.h>
#include <hip/hip_bf16.h>

// ---------- types ----------
typedef short bf16x8 __attribute__((ext_vector_type(8)));
typedef float f32x4 __attribute__((ext_vector_type(4)));

#define NB 4
#define C 256
#define HW 4096
#define NROWS (NB * HW)   // 16384
#define EPSF 1e-5f

// ---------- helpers ----------
__device__ __forceinline__ unsigned short f2bf(float f) {
    unsigned int u = __float_as_uint(f);
    unsigned int r = u + 0x7fffu + ((u >> 16) & 1u);
    return (unsigned short)(r >> 16);
}
__device__ __forceinline__ float bf2f(unsigned int h) {
    return __uint_as_float(h << 16);
}
__device__ __forceinline__ void unpack8(uint4 u, float* v) {
    unsigned int w0 = u.x, w1 = u.y, w2 = u.z, w3 = u.w;
    v[0] = bf2f(w0 & 0xffffu); v[1] = bf2f(w0 >> 16);
    v[2] = bf2f(w1 & 0xffffu); v[3] = bf2f(w1 >> 16);
    v[4] = bf2f(w2 & 0xffffu); v[5] = bf2f(w2 >> 16);
    v[6] = bf2f(w3 & 0xffffu); v[7] = bf2f(w3 >> 16);
}
__device__ __forceinline__ float waveReduceSum(float v) {
    for (int off = 32; off > 0; off >>= 1) v += __shfl_xor(v, off);
    return v;
}
__device__ __forceinline__ float waveReduceMax(float v) {
    for (int off = 32; off > 0; off >>= 1) v = fmaxf(v, __shfl_xor(v, off));
    return v;
}
// async global->LDS 16B copy; lds ptr must be wave-uniform-base + lane*16
typedef __attribute__((address_space(1))) const unsigned int glb_cu;
typedef __attribute__((address_space(3))) unsigned int lds_u;
__device__ __forceinline__ void async_copy16(const unsigned short* g, unsigned short* l) {
    __builtin_amdgcn_global_load_lds((glb_cu*)g, (lds_u*)l, 16, 0, 0);
}

// ---------- K1: per-channel mean of y ----------
__global__ __launch_bounds__(256) void mu_kernel(const float* __restrict__ y,
                                                 float* __restrict__ mu) {
    int c = blockIdx.x;
    int tid = threadIdx.x;
    float s = 0.f;
    const float* base = y + (size_t)c * HW;
    for (int n = 0; n < NB; n++) {
        const float* bn = base + (size_t)n * C * HW;
        for (int i = tid; i < HW; i += 256) s += bn[i];
    }
    s = waveReduceSum(s);
    __shared__ float red[4];
    int lane = tid & 63, wave = tid >> 6;
    if (lane == 0) red[wave] = s;
    __syncthreads();
    if (tid == 0) mu[c] = (red[0] + red[1] + red[2] + red[3]) * (1.0f / 16384.0f);
}

// ---------- K2: center, L2-normalize over C, transpose to (n,p,c) bf16 ----------
#define TP 32
#define TSTRIDE 257
__global__ __launch_bounds__(256) void prep_kernel(const float* __restrict__ x,
                                                   const float* __restrict__ y,
                                                   const float* __restrict__ mu,
                                                   unsigned short* __restrict__ Xn,
                                                   unsigned short* __restrict__ Yn) {
    __shared__ float smu[C];
    __shared__ float tile[TP * TSTRIDE];
    __shared__ float red[8 * 32];
    __shared__ float invn[TP];
    int tid = threadIdx.x;
    smu[tid] = mu[tid];
    int blk = blockIdx.x;
    int n = blk >> 7;                // 128 blocks per batch
    int p0 = (blk & 127) * TP;
    int tp = tid & 31, cc = tid >> 5;
    __syncthreads();
    for (int pass = 0; pass < 2; pass++) {
        const float* in = pass ? y : x;
        unsigned short* out = pass ? Yn : Xn;
        const float* base = in + (size_t)n * C * HW + p0 + tp;
        float ssq = 0.f;
        for (int c = cc; c < C; c += 8) {
            float v = base[(size_t)c * HW] - smu[c];
            tile[tp * TSTRIDE + c] = v;
            ssq += v * v;
        }
        red[cc * 32 + tp] = ssq;
        __syncthreads();
        if (tid < 32) {
            float s = 0.f;
            for (int k = 0; k < 8; k++) s += red[k * 32 + tid];
            invn[tid] = rsqrtf(s);
        }
        __syncthreads();
        int c2 = (tid & 127) * 2;
        int pp = tid >> 7;
        for (int p = pp; p < TP; p += 2) {
            float inv = invn[p];
            unsigned short b0 = f2bf(tile[p * TSTRIDE + c2] * inv);
            unsigned short b1 = f2bf(tile[p * TSTRIDE + c2 + 1] * inv);
            unsigned int pack = (unsigned int)b0 | ((unsigned int)b1 << 16);
            ((unsigned int*)out)[(size_t)(n * HW + p0 + p) * (C / 2) + (c2 >> 1)] = pack;
        }
        __syncthreads();
    }
}

// ---------- K3: batched GEMM cos = Xn * Yn^T, bf16 out ----------
// 128x128 tile, K=256 in two halves of 128. global_load_lds staging into
// XOR-swizzled LDS; 64KB LDS -> 2 blocks/CU. Epilogue transposes through LDS
// for coalesced dwordx4 stores.
#define EPSTRIDE 136
__global__ __launch_bounds__(256, 2) void gemm_cos(const unsigned short* __restrict__ Xn,
                                                   const unsigned short* __restrict__ Yn,
                                                   unsigned short* __restrict__ Cos) {
    __shared__ unsigned short lds_us[32768];   // 64 KB: A[16K ushorts] B[16K]
    int n = blockIdx.z;
    int pBase = blockIdx.y * 128, qBase = blockIdx.x * 128;
    const unsigned short* Ab = Xn + ((size_t)n * HW + pBase) * C;
    const unsigned short* Bb = Yn + ((size_t)n * HW + qBase) * C;
    int tid = threadIdx.x, lane = tid & 63, wave = tid >> 6;
    int wm = (wave >> 1) * 64, wn = (wave & 1) * 64;
    int mrow = lane & 15, quad = lane >> 4;

    f32x4 acc[4][4];
#pragma unroll
    for (int i = 0; i < 4; i++)
#pragma unroll
        for (int j = 0; j < 4; j++) acc[i][j] = (f32x4){0.f, 0.f, 0.f, 0.f};

#pragma unroll
    for (int h = 0; h < 2; h++) {
#pragma unroll
        for (int mat = 0; mat < 2; mat++) {
            const unsigned short* g = mat ? Bb : Ab;
            unsigned short* lbase = lds_us + mat * 16384;
#pragma unroll
            for (int t = 0; t < 8; t++) {
                int slot = t * 256 + tid;           // 0..2047
                int r = slot >> 4, cl = slot & 15;
                int c = h * 16 + (cl ^ (r & 15));   // global 16B-chunk index
                async_copy16(g + (size_t)r * C + c * 8, lbase + slot * 8);
            }
        }
        __syncthreads();
#pragma unroll
        for (int kkl = 0; kkl < 4; kkl++) {
            int cl4 = kkl * 4 + quad;
            int clp = cl4 ^ mrow;
            bf16x8 af[4], bfr[4];
#pragma unroll
            for (int i = 0; i < 4; i++) {
                af[i]  = *(const bf16x8*)(lds_us + (wm + i * 16 + mrow) * 128 + clp * 8);
                bfr[i] = *(const bf16x8*)(lds_us + 16384 + (wn + i * 16 + mrow) * 128 + clp * 8);
            }
#pragma unroll
            for (int i = 0; i < 4; i++)
#pragma unroll
                for (int j = 0; j < 4; j++)
                    acc[i][j] = __builtin_amdgcn_mfma_f32_16x16x32_bf16(af[i], bfr[j], acc[i][j], 0, 0, 0);
        }
        __syncthreads();
    }

    // ---- epilogue: transpose through LDS (bf16), coalesced dwordx4 stores ----
    unsigned short* epb = lds_us;  // 128 x EPSTRIDE bf16 = 34 KB
    int col = lane & 15, quad4 = quad * 4;
#pragma unroll
    for (int i = 0; i < 4; i++)
#pragma unroll
        for (int j = 0; j < 4; j++)
#pragma unroll
            for (int r = 0; r < 4; r++)
                epb[(wm + i * 16 + quad4 + r) * EPSTRIDE + wn + j * 16 + col] = f2bf(acc[i][j][r]);
    __syncthreads();
    unsigned short* Crow = Cos + (size_t)n * HW * HW;
#pragma unroll
    for (int it = 0; it < 8; it++) {
        int e = it * 2048 + tid * 8;
        int r = e >> 7, cg = e & 127;
        uint4 o = *(const uint4*)(epb + r * EPSTRIDE + cg);
        *(uint4*)(Crow + (size_t)(pBase + r) * HW + qBase + cg) = o;
    }
}

// ---------- K4: fused row stats + column logit-max, STREAMING (4 rows/group) ----------
// Block owns 16 rows; processes 4 at a time: load->unpack->rowmax->alpha->
// expsum->beta->column logit-max. 8 barriers/block total; ~32 data regs live
// per group. Column maxes go straight to global via ordered-uint atomicMax.
__global__ __launch_bounds__(256) void rowcol(const unsigned short* __restrict__ Cos,
                                              unsigned int* __restrict__ colkey) {
    int n = blockIdx.y, chunk = blockIdx.x;   // 0..255, 16 rows each
    int tid = threadIdx.x, lane = tid & 63, wave = tid >> 6;
    const unsigned short* rowbase = Cos + ((size_t)n * HW + chunk * 16) * HW;
    __shared__ float redm[4][4];
    __shared__ float sval[4][4];
    float cmax[16];
#pragma unroll
    for (int k = 0; k < 16; k++) cmax[k] = -1e30f;

#pragma unroll
    for (int g = 0; g < 4; g++) {
        uint4 da[4], db[4];
#pragma unroll
        for (int r = 0; r < 4; r++) {
            const unsigned short* rp = rowbase + (size_t)(g * 4 + r) * HW;
            da[r] = *(const uint4*)(rp + tid * 8);
            db[r] = *(const uint4*)(rp + 2048 + tid * 8);
        }
        float v[4][16];
#pragma unroll
        for (int r = 0; r < 4; r++) { unpack8(da[r], v[r]); unpack8(db[r], v[r] + 8); }
        // batched row maxes (independent reduction chains)
#pragma unroll
        for (int r = 0; r < 4; r++) {
            float m = v[r][0];
#pragma unroll
            for (int k = 1; k < 16; k++) m = fmaxf(m, v[r][k]);
            m = waveReduceMax(m);
            if (lane == 0) redm[r][wave] = m;
        }
        __syncthreads();
        float alpha[4], basec[4];
#pragma unroll
        for (int r = 0; r < 4; r++) {
            float M = fmaxf(fmaxf(redm[r][0], redm[r][1]), fmaxf(redm[r][2], redm[r][3]));
            alpha[r] = 2.0f / ((1.0f - M) + EPSF);
            basec[r] = 2.0f - alpha[r];
        }
        // batched exp row-sums
#pragma unroll
        for (int r = 0; r < 4; r++) {
            float s = 0.f;
#pragma unroll
            for (int k = 0; k < 16; k++) s += __expf(fmaf(alpha[r], v[r][k], basec[r]));
            s = waveReduceSum(s);
            if (lane == 0) sval[r][wave] = s;
        }
        __syncthreads();
#pragma unroll
        for (int r = 0; r < 4; r++) {
            float S = sval[r][0] + sval[r][1] + sval[r][2] + sval[r][3];
            float beta = basec[r] - __logf(S);
#pragma unroll
            for (int k = 0; k < 16; k++) cmax[k] = fmaxf(cmax[k], fmaf(alpha[r], v[r][k], beta));
        }
        // no extra barrier: redm rewrite (next g) is after this group's bar2;
        // sval rewrite is after next group's bar1.
    }
    unsigned int* ck = colkey + (size_t)n * HW;
#pragma unroll
    for (int k = 0; k < 16; k++) {
        int q = (k < 8) ? (tid * 8 + k) : (2048 + tid * 8 + (k - 8));
        unsigned int b = __float_as_uint(cmax[k]);
        unsigned int key = (b & 0x80000000u) ? ~b : (b | 0x80000000u);
        atomicMax(&ck[q], key);
    }
}

// ---------- K5: decode column keys, exp, sum over q (one block per batch) ----------
__global__ __launch_bounds__(1024) void colfinal(const unsigned int* __restrict__ colkey,
                                                 float* __restrict__ cxsum) {
    int n = blockIdx.x;
    int tid = threadIdx.x;
    float s = 0.f;
    for (int q = tid; q < HW; q += 1024) {
        unsigned int key = colkey[(size_t)n * HW + q];
        unsigned int b = (key & 0x80000000u) ? (key ^ 0x80000000u) : ~key;
        s += __expf(__uint_as_float(b));
    }
    s = waveReduceSum(s);
    __shared__ float red[16];
    int lane = tid & 63, wave = tid >> 6;
    if (lane == 0) red[wave] = s;
    __syncthreads();
    if (tid == 0) {
        float S = 0.f;
        for (int w = 0; w < 16; w++) S += red[w];
        cxsum[n] = S;
    }
}

// ---------- K6: final loss ----------
__global__ void finalize(const float* __restrict__ cxsum, float* __restrict__ out) {
    if (threadIdx.x == 0 && blockIdx.x == 0) {
        float loss = 0.f;
        for (int n = 0; n < NB; n++) {
            float cx = cxsum[n] * (1.0f / 4096.0f);
            loss += -logf(cx + EPSF);
        }
        out[0] = loss * 0.25f;
    }
}

// ---------- launch ----------
extern "C" void kernel_launch(void* const* d_in, const int* in_sizes, int n_in,
                              void* d_out, int out_size, void* d_ws, size_t ws_size,
                              hipStream_t stream) {
    const float* x = (const float*)d_in[0];
    const float* y = (const float*)d_in[1];
    float* out = (float*)d_out;
    char* ws = (char*)d_ws;

    float* mu            = (float*)(ws + 0);                   // 1 KiB
    float* cxsum         = (float*)(ws + 1024);                // 16 B
    unsigned int* colkey = (unsigned int*)(ws + 4096);         // 64 KiB
    unsigned short* Xn   = (unsigned short*)(ws + 2097152);    // 8 MiB
    unsigned short* Yn   = (unsigned short*)(ws + 10485760);   // 8 MiB
    unsigned short* Cos  = (unsigned short*)(ws + 18874368);   // 128 MiB

    hipMemsetAsync(colkey, 0, NB * HW * sizeof(unsigned int), stream);

    mu_kernel<<<C, 256, 0, stream>>>(y, mu);
    prep_kernel<<<NROWS / TP, 256, 0, stream>>>(x, y, mu, Xn, Yn);
    gemm_cos<<<dim3(HW / 128, HW / 128, NB), 256, 0, stream>>>(Xn, Yn, Cos);
    rowcol<<<dim3(256, NB), 256, 0, stream>>>(Cos, colkey);
    colfinal<<<NB, 1024, 0, stream>>>(colkey, cxsum);
    finalize<<<1, 64, 0, stream>>>(cxsum, out);
}